// Round 6
// baseline (562.819 us; speedup 1.0000x reference)
//
#include <hip/hip_runtime.h>

// TransformerBlock: B=2, T=2048, D=1024, H=16, Dh=64, Dff=4096. All inputs fp32.
// Strategy: bf16 MFMA everywhere; weights transposed+converted on device each call.

typedef unsigned short u16;
typedef __attribute__((ext_vector_type(8))) short     bf16x8;
typedef __attribute__((ext_vector_type(4))) float     f32x4;
typedef __attribute__((ext_vector_type(8))) unsigned short u16x8;
typedef __attribute__((ext_vector_type(4))) unsigned short u16x4;

__device__ __forceinline__ u16 f2bf(float f) {
    unsigned u = __builtin_bit_cast(unsigned, f);
    unsigned r = (u + 0x7fffu + ((u >> 16) & 1u)) >> 16;
    return (u16)r;
}
__device__ __forceinline__ float bf2f(u16 h) {
    unsigned u = ((unsigned)h) << 16;
    return __builtin_bit_cast(float, u);
}
__device__ __forceinline__ f32x4 mfma16(bf16x8 a, bf16x8 b, f32x4 c) {
    return __builtin_amdgcn_mfma_f32_16x16x32_bf16(a, b, c, 0, 0, 0);
}
__device__ __forceinline__ void gl_lds16(const u16* g, u16* l) {
    __builtin_amdgcn_global_load_lds((const __attribute__((address_space(1))) void*)g,
                                     (__attribute__((address_space(3))) void*)l, 16, 0, 0);
}

// ---------------- weight transpose + fp32->bf16 convert: in[R][C] f32 -> out[C][R] bf16
__global__ __launch_bounds__(256) void wconv_kernel(const float* __restrict__ in, u16* __restrict__ out,
                                                    int R, int C) {
    __shared__ float t[32][33];
    const int tx = threadIdx.x, ty = threadIdx.y;
    const int c0 = blockIdx.x * 32, r0 = blockIdx.y * 32;
#pragma unroll
    for (int i = 0; i < 4; ++i)
        t[ty + 8 * i][tx] = in[(size_t)(r0 + ty + 8 * i) * C + c0 + tx];
    __syncthreads();
#pragma unroll
    for (int i = 0; i < 4; ++i)
        out[(size_t)(c0 + ty + 8 * i) * R + r0 + tx] = f2bf(t[tx][ty + 8 * i]);
}

// ---------------- layernorm: x[row][1024] f32 -> out bf16
__global__ __launch_bounds__(256) void ln_kernel(const float* __restrict__ x, const float* __restrict__ g,
                                                 const float* __restrict__ b, u16* __restrict__ out) {
    const int row = blockIdx.x, tid = threadIdx.x;
    const float4 v = ((const float4*)(x + (size_t)row * 1024))[tid];
    float s = v.x + v.y + v.z + v.w;
    float q = v.x * v.x + v.y * v.y + v.z * v.z + v.w * v.w;
#pragma unroll
    for (int o = 32; o; o >>= 1) { s += __shfl_xor(s, o); q += __shfl_xor(q, o); }
    __shared__ float red[8];
    if ((tid & 63) == 0) { red[(tid >> 6) * 2] = s; red[(tid >> 6) * 2 + 1] = q; }
    __syncthreads();
    s = red[0] + red[2] + red[4] + red[6];
    q = red[1] + red[3] + red[5] + red[7];
    const float mu = s * (1.0f / 1024.0f);
    const float var = q * (1.0f / 1024.0f) - mu * mu;
    const float rs = rsqrtf(var + 1e-5f);
    const float4 gv = ((const float4*)g)[tid];
    const float4 bv = ((const float4*)b)[tid];
    u16x4 o;
    o[0] = f2bf((v.x - mu) * rs * gv.x + bv.x);
    o[1] = f2bf((v.y - mu) * rs * gv.y + bv.y);
    o[2] = f2bf((v.z - mu) * rs * gv.z + bv.z);
    o[3] = f2bf((v.w - mu) * rs * gv.w + bv.w);
    ((u16x4*)(out + (size_t)row * 1024))[tid] = o;
}

// ---------------- GEMM: C[M,N] = A[M,K](bf16) @ Bt[N,K](bf16)^T, epilogues.
// MODE 0: bf16 out, +bias.  MODE 1: bf16 out, +bias, relu.  MODE 2: f32 out, +bias, +resid[M,N].
template <int MODE>
__global__ __launch_bounds__(256) void gemm_kernel(const u16* __restrict__ A, const u16* __restrict__ Bt,
                                                   const float* __restrict__ bias, const float* __restrict__ resid,
                                                   void* __restrict__ Cout, int M, int N, int K) {
    __shared__ __align__(16) u16 lds[2][2][4096];  // [buf][A/B][128*32]
    const int tid = threadIdx.x, lane = tid & 63, wid = tid >> 6;
    const int wr = wid >> 1, wc = wid & 1, lg = lane >> 4, lc = lane & 15;
    const int m0 = blockIdx.x * 128, n0 = blockIdx.y * 128;

    const u16* ga0 = A + (size_t)(m0 + (tid >> 2)) * K + (tid & 3) * 8;
    const u16* gb0 = Bt + (size_t)(n0 + (tid >> 2)) * K + (tid & 3) * 8;

    f32x4 acc[4][4];
#pragma unroll
    for (int m = 0; m < 4; ++m)
#pragma unroll
        for (int n = 0; n < 4; ++n) acc[m][n] = (f32x4){0.f, 0.f, 0.f, 0.f};

    const int NT = K >> 5;
    auto stage = [&](int buf, int kt) {
        const u16* ga = ga0 + kt * 32;
        const u16* gb = gb0 + kt * 32;
        gl_lds16(ga, &lds[buf][0][tid * 8]);
        gl_lds16(ga + (size_t)64 * K, &lds[buf][0][2048 + tid * 8]);
        gl_lds16(gb, &lds[buf][1][tid * 8]);
        gl_lds16(gb + (size_t)64 * K, &lds[buf][1][2048 + tid * 8]);
    };
    stage(0, 0);
    for (int kt = 0; kt < NT; ++kt) {
        __syncthreads();  // staging of buf[kt&1] complete (vmcnt drained at barrier)
        if (kt + 1 < NT) stage((kt + 1) & 1, kt + 1);
        const u16* la = &lds[kt & 1][0][0];
        const u16* lb = &lds[kt & 1][1][0];
        bf16x8 a[4], bb[4];
#pragma unroll
        for (int m = 0; m < 4; ++m) a[m] = *(const bf16x8*)(la + (wr * 64 + m * 16 + lc) * 32 + lg * 8);
#pragma unroll
        for (int n = 0; n < 4; ++n) bb[n] = *(const bf16x8*)(lb + (wc * 64 + n * 16 + lc) * 32 + lg * 8);
#pragma unroll
        for (int m = 0; m < 4; ++m)
#pragma unroll
            for (int n = 0; n < 4; ++n) acc[m][n] = mfma16(a[m], bb[n], acc[m][n]);
    }
    // epilogue: C/D layout col=lane&15, row=(lane>>4)*4+reg
#pragma unroll
    for (int m = 0; m < 4; ++m) {
        const int row = m0 + wr * 64 + m * 16 + lg * 4;
#pragma unroll
        for (int n = 0; n < 4; ++n) {
            const int col = n0 + wc * 64 + n * 16 + lc;
            const float bv = bias[col];
#pragma unroll
            for (int r = 0; r < 4; ++r) {
                float v = acc[m][n][r] + bv;
                if (MODE == 1) v = fmaxf(v, 0.0f);
                if (MODE == 2) {
                    v += resid[(size_t)(row + r) * N + col];
                    ((float*)Cout)[(size_t)(row + r) * N + col] = v;
                } else {
                    ((u16*)Cout)[(size_t)(row + r) * N + col] = f2bf(v);
                }
            }
        }
    }
}

// ---------------- V transpose: qkv[token][2048 + h*64 + d] -> v_t[bh][d][t]
__global__ __launch_bounds__(256) void vtrans_kernel(const u16* __restrict__ qkv, u16* __restrict__ v_t) {
    __shared__ u16 tile[64][72];
    const int bh = blockIdx.x >> 5, tt = blockIdx.x & 31;
    const int b = bh >> 4, h = bh & 15, t0 = tt * 64;
    const int tid = threadIdx.x;
    {
        const int tl = tid >> 2, seg = (tid & 3) * 16;
        const u16* src = qkv + (size_t)(b * 2048 + t0 + tl) * 3072 + 2048 + h * 64 + seg;
        u16x8 a = *(const u16x8*)src;
        u16x8 c = *(const u16x8*)(src + 8);
#pragma unroll
        for (int j = 0; j < 8; ++j) { tile[tl][seg + j] = a[j]; tile[tl][seg + 8 + j] = c[j]; }
    }
    __syncthreads();
    {
        const int d = tid >> 2, ts = (tid & 3) * 16;
        u16x8 o0, o1;
#pragma unroll
        for (int j = 0; j < 8; ++j) { o0[j] = tile[ts + j][d]; o1[j] = tile[ts + 8 + j][d]; }
        u16* dst = v_t + ((size_t)bh * 64 + d) * 2048 + t0 + ts;
        *(u16x8*)dst = o0;
        *(u16x8*)(dst + 8) = o1;
    }
}

// ---------------- flash attention (causal), transposed orientation, KV-split over 4 waves.
// Block = one (bh, q-tile of 64). Wave w handles kv-tiles kt ≡ w (mod 4), each with its own
// online softmax (m,l,O). S' = K@Q^T so softmax reduce = 2 shfl_xor. P' roundtrip through
// per-wave transposed LDS [q][kv] (b64 writes / b128 reads, conflict-minimal). At the end the
// 4 partials are merged through LDS. Masked entries use -1e30 (NOT -inf: a wave's first tile
// can be fully masked under kv-split; -inf would NaN the rescale; -1e30 partials get weight
// exp(-1e30 - M) = 0 in the merge, exact).
__global__ __launch_bounds__(256, 4) void attn_kernel(const u16* __restrict__ qkv, const u16* __restrict__ v_t,
                                                      u16* __restrict__ attnb) {
    __shared__ __align__(16) u16 wbuf[4][64 * 72];  // per-wave: P'[64][40] during loop, then pO[64][72]
    __shared__ float ml[4][2][64];
    const int tid = threadIdx.x, lane = tid & 63, wid = tid >> 6;
    const int lg = lane >> 4, lc = lane & 15;
    // XCD-aware swizzle: 1024 blocks, 8 XCDs, 128 consecutive logical blocks (= 4 bh) per XCD.
    const int swz = (blockIdx.x & 7) * 128 + (blockIdx.x >> 3);
    const int qt = swz & 31, bh = swz >> 5;
    const int b = bh >> 4, h = bh & 15;
    const int q0 = qt * 64;
    u16* pl = &wbuf[wid][0];

    const u16* qbase = qkv + (size_t)b * 2048 * 3072 + h * 64;
    const u16* kbase = qbase + 1024;

    bf16x8 qf[2][4];
#pragma unroll
    for (int ks = 0; ks < 2; ++ks)
#pragma unroll
        for (int nf = 0; nf < 4; ++nf)
            qf[ks][nf] = *(const bf16x8*)(qbase + (size_t)(q0 + nf * 16 + lc) * 3072 + ks * 32 + lg * 8);

    f32x4 o[4][4];
#pragma unroll
    for (int i = 0; i < 4; ++i)
#pragma unroll
        for (int j = 0; j < 4; ++j) o[i][j] = (f32x4){0.f, 0.f, 0.f, 0.f};
    float mrow[4] = {-1e30f, -1e30f, -1e30f, -1e30f};
    float lrow[4] = {0.f, 0.f, 0.f, 0.f};

    const int nkt = 2 * qt + 2;
    for (int kt = wid; kt < nkt; kt += 4) {
        const int t0 = kt * 32;
        f32x4 s[2][4];
#pragma unroll
        for (int mf = 0; mf < 2; ++mf)
#pragma unroll
            for (int nf = 0; nf < 4; ++nf) s[mf][nf] = (f32x4){0.f, 0.f, 0.f, 0.f};
#pragma unroll
        for (int mf = 0; mf < 2; ++mf) {
            bf16x8 k0 = *(const bf16x8*)(kbase + (size_t)(t0 + mf * 16 + lc) * 3072 + lg * 8);
            bf16x8 k1 = *(const bf16x8*)(kbase + (size_t)(t0 + mf * 16 + lc) * 3072 + 32 + lg * 8);
#pragma unroll
            for (int nf = 0; nf < 4; ++nf) {
                s[mf][nf] = mfma16(k0, qf[0][nf], s[mf][nf]);
                s[mf][nf] = mfma16(k1, qf[1][nf], s[mf][nf]);
            }
        }
        const bool diag = (kt >= 2 * qt);
#pragma unroll
        for (int mf = 0; mf < 2; ++mf)
#pragma unroll
            for (int nf = 0; nf < 4; ++nf)
#pragma unroll
                for (int r = 0; r < 4; ++r) {
                    float v = s[mf][nf][r] * 0.125f;
                    if (diag) {
                        const int kv = t0 + mf * 16 + lg * 4 + r;
                        const int qq = q0 + nf * 16 + lc;
                        if (kv > qq) v = -1e30f;
                    }
                    s[mf][nf][r] = v;
                }
#pragma unroll
        for (int nf = 0; nf < 4; ++nf) {
            float cm = s[0][nf][0];
#pragma unroll
            for (int mf = 0; mf < 2; ++mf)
#pragma unroll
                for (int r = 0; r < 4; ++r) cm = fmaxf(cm, s[mf][nf][r]);
            cm = fmaxf(cm, __shfl_xor(cm, 16));
            cm = fmaxf(cm, __shfl_xor(cm, 32));
            const float mn = fmaxf(mrow[nf], cm);
            const float fac = __expf(mrow[nf] - mn);
            mrow[nf] = mn;
            float cs = 0.f;
#pragma unroll
            for (int mf = 0; mf < 2; ++mf)
#pragma unroll
                for (int r = 0; r < 4; ++r) {
                    const float p = __expf(s[mf][nf][r] - mn);
                    s[mf][nf][r] = p;
                    cs += p;
                }
            cs += __shfl_xor(cs, 16);
            cs += __shfl_xor(cs, 32);
            lrow[nf] = lrow[nf] * fac + cs;
#pragma unroll
            for (int mf2 = 0; mf2 < 4; ++mf2) o[mf2][nf] *= fac;
            // P' store, transposed [q][kv], stride 40 u16 (80B: 16B-aligned rows, b64-min banks)
#pragma unroll
            for (int mf = 0; mf < 2; ++mf) {
                u16x4 pk;
                pk[0] = f2bf(s[mf][nf][0]);
                pk[1] = f2bf(s[mf][nf][1]);
                pk[2] = f2bf(s[mf][nf][2]);
                pk[3] = f2bf(s[mf][nf][3]);
                *(u16x4*)(pl + (nf * 16 + lc) * 40 + mf * 16 + lg * 4) = pk;
            }
        }
        // B-frags of P': lane needs k = lg*8+j at col q = nf*16+lc  -> one b128 per nf
        bf16x8 pb[4];
#pragma unroll
        for (int nf = 0; nf < 4; ++nf)
            pb[nf] = *(const bf16x8*)(pl + (nf * 16 + lc) * 40 + lg * 8);
#pragma unroll
        for (int mf2 = 0; mf2 < 4; ++mf2) {
            bf16x8 vf = *(const bf16x8*)(v_t + ((size_t)bh * 64 + mf2 * 16 + lc) * 2048 + t0 + lg * 8);
#pragma unroll
            for (int nf = 0; nf < 4; ++nf) o[mf2][nf] = mfma16(vf, pb[nf], o[mf2][nf]);
        }
    }
    // ---- write partial O (unnormalized, bf16) + (m,l) to LDS; own P region is dead.
    u16* po = &wbuf[wid][0];  // [64 q][72 d] u16
#pragma unroll
    for (int mf2 = 0; mf2 < 4; ++mf2)
#pragma unroll
        for (int nf = 0; nf < 4; ++nf) {
            u16x4 pk;
            pk[0] = f2bf(o[mf2][nf][0]);
            pk[1] = f2bf(o[mf2][nf][1]);
            pk[2] = f2bf(o[mf2][nf][2]);
            pk[3] = f2bf(o[mf2][nf][3]);
            *(u16x4*)(po + (nf * 16 + lc) * 72 + mf2 * 16 + lg * 4) = pk;
        }
    if (lg == 0) {
#pragma unroll
        for (int nf = 0; nf < 4; ++nf) {
            ml[wid][0][nf * 16 + lc] = mrow[nf];
            ml[wid][1][nf * 16 + lc] = lrow[nf];
        }
    }
    __syncthreads();
    // ---- merge the 4 partials; item = (q, d-octet), 512 items over 256 threads.
#pragma unroll
    for (int rep = 0; rep < 2; ++rep) {
        const int it = tid + rep * 256;
        const int q = it >> 3, oc = it & 7;
        float mv[4], lv[4];
#pragma unroll
        for (int w = 0; w < 4; ++w) { mv[w] = ml[w][0][q]; lv[w] = ml[w][1][q]; }
        const float M = fmaxf(fmaxf(mv[0], mv[1]), fmaxf(mv[2], mv[3]));
        float fw[4], L = 0.f;
#pragma unroll
        for (int w = 0; w < 4; ++w) { fw[w] = __expf(mv[w] - M); L += lv[w] * fw[w]; }
        const float invL = 1.0f / L;
        float acc[8] = {0.f, 0.f, 0.f, 0.f, 0.f, 0.f, 0.f, 0.f};
#pragma unroll
        for (int w = 0; w < 4; ++w) {
            u16x8 v = *(const u16x8*)(&wbuf[w][q * 72 + oc * 8]);
#pragma unroll
            for (int j = 0; j < 8; ++j) acc[j] += bf2f(v[j]) * fw[w];
        }
        u16x8 ov;
#pragma unroll
        for (int j = 0; j < 8; ++j) ov[j] = f2bf(acc[j] * invL);
        *(u16x8*)(attnb + (size_t)(b * 2048 + q0 + q) * 1024 + h * 64 + oc * 8) = ov;
    }
}

extern "C" void kernel_launch(void* const* d_in, const int* in_sizes, int n_in,
                              void* d_out, int out_size, void* d_ws, size_t ws_size,
                              hipStream_t stream) {
    const float* x = (const float*)d_in[0];
    const float* ln1_g = (const float*)d_in[1];
    const float* ln1_b = (const float*)d_in[2];
    const float* w_qkv = (const float*)d_in[3];
    const float* b_qkv = (const float*)d_in[4];
    const float* w_out = (const float*)d_in[5];
    const float* b_out = (const float*)d_in[6];
    const float* ln2_g = (const float*)d_in[7];
    const float* ln2_b = (const float*)d_in[8];
    const float* w_ff1 = (const float*)d_in[9];
    const float* b_ff1 = (const float*)d_in[10];
    const float* w_ff2 = (const float*)d_in[11];
    const float* b_ff2 = (const float*)d_in[12];
    float* out = (float*)d_out;
    char* ws = (char*)d_ws;

    // workspace layout (bytes), total 96 MiB. ff1 aliases h1+qkv (dead by GEMM3).
    u16* wTqkv = (u16*)(ws + 0);          // [3072][1024] bf16, 6 MiB
    u16* wTout = (u16*)(ws + 6291456);    // [1024][1024], 2 MiB
    u16* wTff1 = (u16*)(ws + 8388608);    // [4096][1024], 8 MiB
    u16* wTff2 = (u16*)(ws + 16777216);   // [1024][4096], 8 MiB
    u16* h1    = (u16*)(ws + 25165824);   // [4096][1024], 8 MiB
    u16* qkv   = (u16*)(ws + 33554432);   // [4096][3072], 24 MiB
    u16* v_t   = (u16*)(ws + 58720256);   // [32][64][2048], 8 MiB
    u16* attnb = (u16*)(ws + 67108864);   // [4096][1024], 8 MiB
    float* x2  = (float*)(ws + 75497472); // [4096][1024] f32, 16 MiB
    u16* h2    = (u16*)(ws + 92274688);   // [4096][1024], 8 MiB
    u16* ff1   = (u16*)(ws + 25165824);   // [4096][4096], 32 MiB (aliases h1+qkv)

    wconv_kernel<<<dim3(96, 32), dim3(32, 8), 0, stream>>>(w_qkv, wTqkv, 1024, 3072);
    wconv_kernel<<<dim3(32, 32), dim3(32, 8), 0, stream>>>(w_out, wTout, 1024, 1024);
    wconv_kernel<<<dim3(128, 32), dim3(32, 8), 0, stream>>>(w_ff1, wTff1, 1024, 4096);
    wconv_kernel<<<dim3(32, 128), dim3(32, 8), 0, stream>>>(w_ff2, wTff2, 4096, 1024);

    ln_kernel<<<4096, 256, 0, stream>>>(x, ln1_g, ln1_b, h1);
    gemm_kernel<0><<<dim3(32, 24), 256, 0, stream>>>(h1, wTqkv, b_qkv, nullptr, qkv, 4096, 3072, 1024);
    vtrans_kernel<<<1024, 256, 0, stream>>>(qkv, v_t);
    attn_kernel<<<1024, 256, 0, stream>>>(qkv, v_t, attnb);
    gemm_kernel<2><<<dim3(32, 8), 256, 0, stream>>>(attnb, wTout, b_out, x, x2, 4096, 1024, 1024);
    ln_kernel<<<4096, 256, 0, stream>>>(x2, ln2_g, ln2_b, h2);
    gemm_kernel<1><<<dim3(32, 32), 256, 0, stream>>>(h2, wTff1, b_ff1, nullptr, ff1, 4096, 4096, 1024);
    gemm_kernel<2><<<dim3(32, 8), 256, 0, stream>>>(ff1, wTff2, b_ff2, x2, out, 4096, 1024, 4096);
}

// Round 8
// 366.203 us; speedup vs baseline: 1.5369x; 1.5369x over previous
//
#include <hip/hip_runtime.h>

// TransformerBlock: B=2, T=2048, D=1024, H=16, Dh=64, Dff=4096. All inputs fp32.
// Strategy: bf16 MFMA everywhere; weights transposed+converted on device each call.

typedef unsigned short u16;
typedef __attribute__((ext_vector_type(8))) short     bf16x8;
typedef __attribute__((ext_vector_type(4))) float     f32x4;
typedef __attribute__((ext_vector_type(8))) unsigned short u16x8;
typedef __attribute__((ext_vector_type(4))) unsigned short u16x4;

__device__ __forceinline__ u16 f2bf(float f) {
    unsigned u = __builtin_bit_cast(unsigned, f);
    unsigned r = (u + 0x7fffu + ((u >> 16) & 1u)) >> 16;
    return (u16)r;
}
__device__ __forceinline__ float bf2f(u16 h) {
    unsigned u = ((unsigned)h) << 16;
    return __builtin_bit_cast(float, u);
}
__device__ __forceinline__ f32x4 mfma16(bf16x8 a, bf16x8 b, f32x4 c) {
    return __builtin_amdgcn_mfma_f32_16x16x32_bf16(a, b, c, 0, 0, 0);
}
__device__ __forceinline__ void gl_lds16(const u16* g, u16* l) {
    __builtin_amdgcn_global_load_lds((const __attribute__((address_space(1))) void*)g,
                                     (__attribute__((address_space(3))) void*)l, 16, 0, 0);
}

// ---------------- weight transpose + fp32->bf16 convert: in[R][C] f32 -> out[C][R] bf16
__global__ __launch_bounds__(256) void wconv_kernel(const float* __restrict__ in, u16* __restrict__ out,
                                                    int R, int C) {
    __shared__ float t[32][33];
    const int tx = threadIdx.x, ty = threadIdx.y;
    const int c0 = blockIdx.x * 32, r0 = blockIdx.y * 32;
#pragma unroll
    for (int i = 0; i < 4; ++i)
        t[ty + 8 * i][tx] = in[(size_t)(r0 + ty + 8 * i) * C + c0 + tx];
    __syncthreads();
#pragma unroll
    for (int i = 0; i < 4; ++i)
        out[(size_t)(c0 + ty + 8 * i) * R + r0 + tx] = f2bf(t[tx][ty + 8 * i]);
}

// ---------------- layernorm: x[row][1024] f32 -> out bf16
__global__ __launch_bounds__(256) void ln_kernel(const float* __restrict__ x, const float* __restrict__ g,
                                                 const float* __restrict__ b, u16* __restrict__ out) {
    const int row = blockIdx.x, tid = threadIdx.x;
    const float4 v = ((const float4*)(x + (size_t)row * 1024))[tid];
    float s = v.x + v.y + v.z + v.w;
    float q = v.x * v.x + v.y * v.y + v.z * v.z + v.w * v.w;
#pragma unroll
    for (int o = 32; o; o >>= 1) { s += __shfl_xor(s, o); q += __shfl_xor(q, o); }
    __shared__ float red[8];
    if ((tid & 63) == 0) { red[(tid >> 6) * 2] = s; red[(tid >> 6) * 2 + 1] = q; }
    __syncthreads();
    s = red[0] + red[2] + red[4] + red[6];
    q = red[1] + red[3] + red[5] + red[7];
    const float mu = s * (1.0f / 1024.0f);
    const float var = q * (1.0f / 1024.0f) - mu * mu;
    const float rs = rsqrtf(var + 1e-5f);
    const float4 gv = ((const float4*)g)[tid];
    const float4 bv = ((const float4*)b)[tid];
    u16x4 o;
    o[0] = f2bf((v.x - mu) * rs * gv.x + bv.x);
    o[1] = f2bf((v.y - mu) * rs * gv.y + bv.y);
    o[2] = f2bf((v.z - mu) * rs * gv.z + bv.z);
    o[3] = f2bf((v.w - mu) * rs * gv.w + bv.w);
    ((u16x4*)(out + (size_t)row * 1024))[tid] = o;
}

// ---------------- GEMM: C[M,N] = A[M,K](bf16) @ Bt[N,K](bf16)^T, epilogues.
// MODE 0: bf16 out, +bias.  MODE 1: bf16 out, +bias, relu.  MODE 2: f32 out, +bias, +resid[M,N].
template <int MODE>
__global__ __launch_bounds__(256) void gemm_kernel(const u16* __restrict__ A, const u16* __restrict__ Bt,
                                                   const float* __restrict__ bias, const float* __restrict__ resid,
                                                   void* __restrict__ Cout, int M, int N, int K) {
    __shared__ __align__(16) u16 lds[2][2][4096];  // [buf][A/B][128*32]
    const int tid = threadIdx.x, lane = tid & 63, wid = tid >> 6;
    const int wr = wid >> 1, wc = wid & 1, lg = lane >> 4, lc = lane & 15;
    const int m0 = blockIdx.x * 128, n0 = blockIdx.y * 128;

    const u16* ga0 = A + (size_t)(m0 + (tid >> 2)) * K + (tid & 3) * 8;
    const u16* gb0 = Bt + (size_t)(n0 + (tid >> 2)) * K + (tid & 3) * 8;

    f32x4 acc[4][4];
#pragma unroll
    for (int m = 0; m < 4; ++m)
#pragma unroll
        for (int n = 0; n < 4; ++n) acc[m][n] = (f32x4){0.f, 0.f, 0.f, 0.f};

    const int NT = K >> 5;
    auto stage = [&](int buf, int kt) {
        const u16* ga = ga0 + kt * 32;
        const u16* gb = gb0 + kt * 32;
        gl_lds16(ga, &lds[buf][0][tid * 8]);
        gl_lds16(ga + (size_t)64 * K, &lds[buf][0][2048 + tid * 8]);
        gl_lds16(gb, &lds[buf][1][tid * 8]);
        gl_lds16(gb + (size_t)64 * K, &lds[buf][1][2048 + tid * 8]);
    };
    stage(0, 0);
    for (int kt = 0; kt < NT; ++kt) {
        __syncthreads();  // staging of buf[kt&1] complete (vmcnt drained at barrier)
        if (kt + 1 < NT) stage((kt + 1) & 1, kt + 1);
        const u16* la = &lds[kt & 1][0][0];
        const u16* lb = &lds[kt & 1][1][0];
        bf16x8 a[4], bb[4];
#pragma unroll
        for (int m = 0; m < 4; ++m) a[m] = *(const bf16x8*)(la + (wr * 64 + m * 16 + lc) * 32 + lg * 8);
#pragma unroll
        for (int n = 0; n < 4; ++n) bb[n] = *(const bf16x8*)(lb + (wc * 64 + n * 16 + lc) * 32 + lg * 8);
#pragma unroll
        for (int m = 0; m < 4; ++m)
#pragma unroll
            for (int n = 0; n < 4; ++n) acc[m][n] = mfma16(a[m], bb[n], acc[m][n]);
    }
    // epilogue: C/D layout col=lane&15, row=(lane>>4)*4+reg
#pragma unroll
    for (int m = 0; m < 4; ++m) {
        const int row = m0 + wr * 64 + m * 16 + lg * 4;
#pragma unroll
        for (int n = 0; n < 4; ++n) {
            const int col = n0 + wc * 64 + n * 16 + lc;
            const float bv = bias[col];
#pragma unroll
            for (int r = 0; r < 4; ++r) {
                float v = acc[m][n][r] + bv;
                if (MODE == 1) v = fmaxf(v, 0.0f);
                if (MODE == 2) {
                    v += resid[(size_t)(row + r) * N + col];
                    ((float*)Cout)[(size_t)(row + r) * N + col] = v;
                } else {
                    ((u16*)Cout)[(size_t)(row + r) * N + col] = f2bf(v);
                }
            }
        }
    }
}

// ---------------- V transpose: qkv[token][2048 + h*64 + d] -> v_t[bh][d][t]
__global__ __launch_bounds__(256) void vtrans_kernel(const u16* __restrict__ qkv, u16* __restrict__ v_t) {
    __shared__ u16 tile[64][72];
    const int bh = blockIdx.x >> 5, tt = blockIdx.x & 31;
    const int b = bh >> 4, h = bh & 15, t0 = tt * 64;
    const int tid = threadIdx.x;
    {
        const int tl = tid >> 2, seg = (tid & 3) * 16;
        const u16* src = qkv + (size_t)(b * 2048 + t0 + tl) * 3072 + 2048 + h * 64 + seg;
        u16x8 a = *(const u16x8*)src;
        u16x8 c = *(const u16x8*)(src + 8);
#pragma unroll
        for (int j = 0; j < 8; ++j) { tile[tl][seg + j] = a[j]; tile[tl][seg + 8 + j] = c[j]; }
    }
    __syncthreads();
    {
        const int d = tid >> 2, ts = (tid & 3) * 16;
        u16x8 o0, o1;
#pragma unroll
        for (int j = 0; j < 8; ++j) { o0[j] = tile[ts + j][d]; o1[j] = tile[ts + 8 + j][d]; }
        u16* dst = v_t + ((size_t)bh * 64 + d) * 2048 + t0 + ts;
        *(u16x8*)dst = o0;
        *(u16x8*)(dst + 8) = o1;
    }
}

// ---------------- flash attention (causal), transposed orientation, KV-split over 4 waves.
// Block = one (bh, q-tile of 64). Wave w handles kv-tiles kt ≡ w (mod 4), each with its own
// online softmax (m,l,O). S' = K@Q^T so softmax reduce = 2 shfl_xor. P' roundtrip through
// per-wave transposed LDS [q][kv] (b64 writes / b128 reads, conflict-minimal). At the end the
// 4 partials are merged through LDS. Masked entries use -1e30 (NOT -inf: a wave's first tile
// can be fully masked under kv-split; -inf would NaN the rescale; -1e30 partials get weight
// exp(-1e30 - M) = 0 in the merge, exact).
// NOTE: plain __launch_bounds__(256). The (256,4) variant capped VGPR at 128 -> allocator
// collapsed to 64 and spilled the o[4][4] accumulators: 520 MB/dispatch scratch traffic,
// 252 us, 100% spill-bound (R6 counters). Live set needs ~124 VGPR (R2: no spill at 124).
__global__ __launch_bounds__(256) void attn_kernel(const u16* __restrict__ qkv, const u16* __restrict__ v_t,
                                                   u16* __restrict__ attnb) {
    __shared__ __align__(16) u16 wbuf[4][64 * 72];  // per-wave: P'[64][40] during loop, then pO[64][72]
    __shared__ float ml[4][2][64];
    const int tid = threadIdx.x, lane = tid & 63, wid = tid >> 6;
    const int lg = lane >> 4, lc = lane & 15;
    // XCD-aware swizzle: 1024 blocks, 8 XCDs, 128 consecutive logical blocks (= 4 bh) per XCD.
    const int swz = (blockIdx.x & 7) * 128 + (blockIdx.x >> 3);
    const int qt = swz & 31, bh = swz >> 5;
    const int b = bh >> 4, h = bh & 15;
    const int q0 = qt * 64;
    u16* pl = &wbuf[wid][0];

    const u16* qbase = qkv + (size_t)b * 2048 * 3072 + h * 64;
    const u16* kbase = qbase + 1024;

    bf16x8 qf[2][4];
#pragma unroll
    for (int ks = 0; ks < 2; ++ks)
#pragma unroll
        for (int nf = 0; nf < 4; ++nf)
            qf[ks][nf] = *(const bf16x8*)(qbase + (size_t)(q0 + nf * 16 + lc) * 3072 + ks * 32 + lg * 8);

    f32x4 o[4][4];
#pragma unroll
    for (int i = 0; i < 4; ++i)
#pragma unroll
        for (int j = 0; j < 4; ++j) o[i][j] = (f32x4){0.f, 0.f, 0.f, 0.f};
    float mrow[4] = {-1e30f, -1e30f, -1e30f, -1e30f};
    float lrow[4] = {0.f, 0.f, 0.f, 0.f};

    const int nkt = 2 * qt + 2;
    for (int kt = wid; kt < nkt; kt += 4) {
        const int t0 = kt * 32;
        f32x4 s[2][4];
#pragma unroll
        for (int mf = 0; mf < 2; ++mf)
#pragma unroll
            for (int nf = 0; nf < 4; ++nf) s[mf][nf] = (f32x4){0.f, 0.f, 0.f, 0.f};
#pragma unroll
        for (int mf = 0; mf < 2; ++mf) {
            bf16x8 k0 = *(const bf16x8*)(kbase + (size_t)(t0 + mf * 16 + lc) * 3072 + lg * 8);
            bf16x8 k1 = *(const bf16x8*)(kbase + (size_t)(t0 + mf * 16 + lc) * 3072 + 32 + lg * 8);
#pragma unroll
            for (int nf = 0; nf < 4; ++nf) {
                s[mf][nf] = mfma16(k0, qf[0][nf], s[mf][nf]);
                s[mf][nf] = mfma16(k1, qf[1][nf], s[mf][nf]);
            }
        }
        const bool diag = (kt >= 2 * qt);
#pragma unroll
        for (int mf = 0; mf < 2; ++mf)
#pragma unroll
            for (int nf = 0; nf < 4; ++nf)
#pragma unroll
                for (int r = 0; r < 4; ++r) {
                    float v = s[mf][nf][r] * 0.125f;
                    if (diag) {
                        const int kv = t0 + mf * 16 + lg * 4 + r;
                        const int qq = q0 + nf * 16 + lc;
                        if (kv > qq) v = -1e30f;
                    }
                    s[mf][nf][r] = v;
                }
#pragma unroll
        for (int nf = 0; nf < 4; ++nf) {
            float cm = s[0][nf][0];
#pragma unroll
            for (int mf = 0; mf < 2; ++mf)
#pragma unroll
                for (int r = 0; r < 4; ++r) cm = fmaxf(cm, s[mf][nf][r]);
            cm = fmaxf(cm, __shfl_xor(cm, 16));
            cm = fmaxf(cm, __shfl_xor(cm, 32));
            const float mn = fmaxf(mrow[nf], cm);
            const float fac = __expf(mrow[nf] - mn);
            mrow[nf] = mn;
            float cs = 0.f;
#pragma unroll
            for (int mf = 0; mf < 2; ++mf)
#pragma unroll
                for (int r = 0; r < 4; ++r) {
                    const float p = __expf(s[mf][nf][r] - mn);
                    s[mf][nf][r] = p;
                    cs += p;
                }
            cs += __shfl_xor(cs, 16);
            cs += __shfl_xor(cs, 32);
            lrow[nf] = lrow[nf] * fac + cs;
#pragma unroll
            for (int mf2 = 0; mf2 < 4; ++mf2) o[mf2][nf] *= fac;
            // P' store, transposed [q][kv], stride 40 u16 (80B: 16B-aligned rows, b64-min banks)
#pragma unroll
            for (int mf = 0; mf < 2; ++mf) {
                u16x4 pk;
                pk[0] = f2bf(s[mf][nf][0]);
                pk[1] = f2bf(s[mf][nf][1]);
                pk[2] = f2bf(s[mf][nf][2]);
                pk[3] = f2bf(s[mf][nf][3]);
                *(u16x4*)(pl + (nf * 16 + lc) * 40 + mf * 16 + lg * 4) = pk;
            }
        }
        // B-frags of P': lane needs k = lg*8+j at col q = nf*16+lc  -> one b128 per nf
        bf16x8 pb[4];
#pragma unroll
        for (int nf = 0; nf < 4; ++nf)
            pb[nf] = *(const bf16x8*)(pl + (nf * 16 + lc) * 40 + lg * 8);
#pragma unroll
        for (int mf2 = 0; mf2 < 4; ++mf2) {
            bf16x8 vf = *(const bf16x8*)(v_t + ((size_t)bh * 64 + mf2 * 16 + lc) * 2048 + t0 + lg * 8);
#pragma unroll
            for (int nf = 0; nf < 4; ++nf) o[mf2][nf] = mfma16(vf, pb[nf], o[mf2][nf]);
        }
    }
    // ---- write partial O (unnormalized, bf16) + (m,l) to LDS; own P region is dead.
    u16* po = &wbuf[wid][0];  // [64 q][72 d] u16
#pragma unroll
    for (int mf2 = 0; mf2 < 4; ++mf2)
#pragma unroll
        for (int nf = 0; nf < 4; ++nf) {
            u16x4 pk;
            pk[0] = f2bf(o[mf2][nf][0]);
            pk[1] = f2bf(o[mf2][nf][1]);
            pk[2] = f2bf(o[mf2][nf][2]);
            pk[3] = f2bf(o[mf2][nf][3]);
            *(u16x4*)(po + (nf * 16 + lc) * 72 + mf2 * 16 + lg * 4) = pk;
        }
    if (lg == 0) {
#pragma unroll
        for (int nf = 0; nf < 4; ++nf) {
            ml[wid][0][nf * 16 + lc] = mrow[nf];
            ml[wid][1][nf * 16 + lc] = lrow[nf];
        }
    }
    __syncthreads();
    // ---- merge the 4 partials; item = (q, d-octet), 512 items over 256 threads.
#pragma unroll
    for (int rep = 0; rep < 2; ++rep) {
        const int it = tid + rep * 256;
        const int q = it >> 3, oc = it & 7;
        float mv[4], lv[4];
#pragma unroll
        for (int w = 0; w < 4; ++w) { mv[w] = ml[w][0][q]; lv[w] = ml[w][1][q]; }
        const float M = fmaxf(fmaxf(mv[0], mv[1]), fmaxf(mv[2], mv[3]));
        float fw[4], L = 0.f;
#pragma unroll
        for (int w = 0; w < 4; ++w) { fw[w] = __expf(mv[w] - M); L += lv[w] * fw[w]; }
        const float invL = 1.0f / L;
        float acc[8] = {0.f, 0.f, 0.f, 0.f, 0.f, 0.f, 0.f, 0.f};
#pragma unroll
        for (int w = 0; w < 4; ++w) {
            u16x8 v = *(const u16x8*)(&wbuf[w][q * 72 + oc * 8]);
#pragma unroll
            for (int j = 0; j < 8; ++j) acc[j] += bf2f(v[j]) * fw[w];
        }
        u16x8 ov;
#pragma unroll
        for (int j = 0; j < 8; ++j) ov[j] = f2bf(acc[j] * invL);
        *(u16x8*)(attnb + (size_t)(b * 2048 + q0 + q) * 1024 + h * 64 + oc * 8) = ov;
    }
}

extern "C" void kernel_launch(void* const* d_in, const int* in_sizes, int n_in,
                              void* d_out, int out_size, void* d_ws, size_t ws_size,
                              hipStream_t stream) {
    const float* x = (const float*)d_in[0];
    const float* ln1_g = (const float*)d_in[1];
    const float* ln1_b = (const float*)d_in[2];
    const float* w_qkv = (const float*)d_in[3];
    const float* b_qkv = (const float*)d_in[4];
    const float* w_out = (const float*)d_in[5];
    const float* b_out = (const float*)d_in[6];
    const float* ln2_g = (const float*)d_in[7];
    const float* ln2_b = (const float*)d_in[8];
    const float* w_ff1 = (const float*)d_in[9];
    const float* b_ff1 = (const float*)d_in[10];
    const float* w_ff2 = (const float*)d_in[11];
    const float* b_ff2 = (const float*)d_in[12];
    float* out = (float*)d_out;
    char* ws = (char*)d_ws;

    // workspace layout (bytes), total 96 MiB. ff1 aliases h1+qkv (dead by GEMM3).
    u16* wTqkv = (u16*)(ws + 0);          // [3072][1024] bf16, 6 MiB
    u16* wTout = (u16*)(ws + 6291456);    // [1024][1024], 2 MiB
    u16* wTff1 = (u16*)(ws + 8388608);    // [4096][1024], 8 MiB
    u16* wTff2 = (u16*)(ws + 16777216);   // [1024][4096], 8 MiB
    u16* h1    = (u16*)(ws + 25165824);   // [4096][1024], 8 MiB
    u16* qkv   = (u16*)(ws + 33554432);   // [4096][3072], 24 MiB
    u16* v_t   = (u16*)(ws + 58720256);   // [32][64][2048], 8 MiB
    u16* attnb = (u16*)(ws + 67108864);   // [4096][1024], 8 MiB
    float* x2  = (float*)(ws + 75497472); // [4096][1024] f32, 16 MiB
    u16* h2    = (u16*)(ws + 92274688);   // [4096][1024], 8 MiB
    u16* ff1   = (u16*)(ws + 25165824);   // [4096][4096], 32 MiB (aliases h1+qkv)

    wconv_kernel<<<dim3(96, 32), dim3(32, 8), 0, stream>>>(w_qkv, wTqkv, 1024, 3072);
    wconv_kernel<<<dim3(32, 32), dim3(32, 8), 0, stream>>>(w_out, wTout, 1024, 1024);
    wconv_kernel<<<dim3(128, 32), dim3(32, 8), 0, stream>>>(w_ff1, wTff1, 1024, 4096);
    wconv_kernel<<<dim3(32, 128), dim3(32, 8), 0, stream>>>(w_ff2, wTff2, 4096, 1024);

    ln_kernel<<<4096, 256, 0, stream>>>(x, ln1_g, ln1_b, h1);
    gemm_kernel<0><<<dim3(32, 24), 256, 0, stream>>>(h1, wTqkv, b_qkv, nullptr, qkv, 4096, 3072, 1024);
    vtrans_kernel<<<1024, 256, 0, stream>>>(qkv, v_t);
    attn_kernel<<<1024, 256, 0, stream>>>(qkv, v_t, attnb);
    gemm_kernel<2><<<dim3(32, 8), 256, 0, stream>>>(attnb, wTout, b_out, x, x2, 4096, 1024, 1024);
    ln_kernel<<<4096, 256, 0, stream>>>(x2, ln2_g, ln2_b, h2);
    gemm_kernel<1><<<dim3(32, 32), 256, 0, stream>>>(h2, wTff1, b_ff1, nullptr, ff1, 4096, 4096, 1024);
    gemm_kernel<2><<<dim3(32, 8), 256, 0, stream>>>(ff1, wTff2, b_ff2, x2, out, 4096, 1024, 4096);
}